// Round 8
// baseline (402.389 us; speedup 1.0000x reference)
//
#include <hip/hip_runtime.h>
#include <hip/hip_bf16.h>

#define TOKENS 16384
#define DIM 1024
#define HID 4096

typedef __attribute__((ext_vector_type(8))) short short8;
typedef __attribute__((ext_vector_type(4))) float f32x4;

__device__ __forceinline__ unsigned short f2bf(float f) {
  union { float f; unsigned int u; } v; v.f = f;
  unsigned int r = v.u + 0x7fffu + ((v.u >> 16) & 1u);
  return (unsigned short)(r >> 16);
}

__device__ __forceinline__ void async16(const void* g, void* lds) {
  __builtin_amdgcn_global_load_lds((const __attribute__((address_space(1))) void*)g,
                                   (__attribute__((address_space(3))) void*)lds, 16, 0, 0);
}

// ---------------------------------------------------------------------------
// Router v3: 16 tokens/block (4 waves x 4 tokens), ALL loads hoisted, 4
// independent fp64 xor-butterfly reduces interleaved (latency hidden).
// Butterfly is commutative-pairing -> bitwise-identical sum in every lane ->
// wave-uniform sel. Selected -> xb bf16; unselected -> out fp32. 1 atomic/blk.
// ---------------------------------------------------------------------------
__global__ __launch_bounds__(256) void router_kernel(
    const float* __restrict__ x, const float* __restrict__ Wr, const float* __restrict__ br,
    float* __restrict__ out, unsigned short* __restrict__ xb,
    int* __restrict__ idx, int* __restrict__ counter)
{
  __shared__ unsigned char selLds[16];
  int wid = threadIdx.x >> 6, lane = threadIdx.x & 63;
  const float4* wr4 = (const float4*)Wr;
  float4 w[4];
#pragma unroll
  for (int j = 0; j < 4; ++j) w[j] = wr4[lane + 64 * j];
  float b0 = br[0];
  int tok0 = blockIdx.x * 16 + wid * 4;

  float4 v[4][4];
#pragma unroll
  for (int t = 0; t < 4; ++t) {
    const float4* xr = (const float4*)(x + (size_t)(tok0 + t) * DIM);
#pragma unroll
    for (int j = 0; j < 4; ++j) v[t][j] = xr[lane + 64 * j];
  }

  double s[4];
#pragma unroll
  for (int t = 0; t < 4; ++t) {
    double acc = 0.0;
#pragma unroll
    for (int j = 0; j < 4; ++j)
      acc += (double)v[t][j].x * w[j].x + (double)v[t][j].y * w[j].y +
             (double)v[t][j].z * w[j].z + (double)v[t][j].w * w[j].w;
    s[t] = acc;
  }
#pragma unroll
  for (int off = 32; off > 0; off >>= 1) {
#pragma unroll
    for (int t = 0; t < 4; ++t) s[t] += __shfl_xor(s[t], off);
  }

  bool sel[4];
#pragma unroll
  for (int t = 0; t < 4; ++t) sel[t] = ((float)s[t] + b0) > 0.0f;  // sigmoid>0.5

#pragma unroll
  for (int t = 0; t < 4; ++t) {
    int token = tok0 + t;
    if (sel[t]) {                                   // wave-uniform branch
      ushort4* xbr = (ushort4*)(xb + (size_t)token * DIM);
#pragma unroll
      for (int j = 0; j < 4; ++j) {
        ushort4 u;
        u.x = f2bf(v[t][j].x); u.y = f2bf(v[t][j].y);
        u.z = f2bf(v[t][j].z); u.w = f2bf(v[t][j].w);
        xbr[lane + 64 * j] = u;
      }
    } else {
      float4* outr = (float4*)(out + (size_t)token * DIM);
#pragma unroll
      for (int j = 0; j < 4; ++j) outr[lane + 64 * j] = v[t][j];
    }
  }
  if (lane == 0) {
#pragma unroll
    for (int t = 0; t < 4; ++t) selLds[wid * 4 + t] = sel[t] ? 1 : 0;
  }
  __syncthreads();
  if (threadIdx.x == 0) {
    int cnt = 0;
#pragma unroll
    for (int i = 0; i < 16; ++i) cnt += selLds[i];
    int p = atomicAdd(counter, cnt);
#pragma unroll
    for (int i = 0; i < 16; ++i)
      if (selLds[i]) idx[p++] = blockIdx.x * 16 + i;
  }
}

// ---------------------------------------------------------------------------
// Transpose + fp32->bf16 cast: W [R][C] fp32 -> Wt [C][R] bf16.
// ---------------------------------------------------------------------------
__global__ __launch_bounds__(256) void transpose_cast_kernel(
    const float* __restrict__ W, unsigned short* __restrict__ Wt, int R, int C)
{
  __shared__ float tile[32][33];
  int tx = threadIdx.x & 31, ty = threadIdx.x >> 5;
  int c0 = blockIdx.x * 32, r0 = blockIdx.y * 32;
#pragma unroll
  for (int i = 0; i < 32; i += 8)
    tile[ty + i][tx] = W[(size_t)(r0 + ty + i) * C + (c0 + tx)];
  __syncthreads();
#pragma unroll
  for (int i = 0; i < 32; i += 8)
    Wt[(size_t)(c0 + ty + i) * R + (r0 + tx)] = f2bf(tile[tx][ty + i]);
}

__global__ void frac_kernel(const int* __restrict__ counter, float* __restrict__ fr)
{
  fr[0] = (float)(*counter) * (1.0f / (float)TOKENS);
}

// ---------------------------------------------------------------------------
// GEMM1: 256x256 8-phase bf16 GEMM (verified correct R4).
// ---------------------------------------------------------------------------
template<int N, int K, bool FIRST>
__global__ __launch_bounds__(512, 2) void gemm8_kernel(
    const unsigned short* __restrict__ A, const unsigned short* __restrict__ Bt,
    const float* __restrict__ bias, const int* __restrict__ idxp,
    const int* __restrict__ counter,
    unsigned short* __restrict__ Hout, float* __restrict__ Cout)
{
  constexpr int NT = N / 256;
  constexpr int NKT = K / 64;
  constexpr int NH = NKT * 4;

  int xcd = blockIdx.x & 7, lin = blockIdx.x >> 3;
  int rowb = (lin / NT) * 8 + xcd;
  int colb = lin % NT;

  int cnt = *counter;
  int row0 = rowb * 256;
  if (row0 >= cnt) return;
  int col0 = colb * 256;

  extern __shared__ unsigned short smem[];
  unsigned short* As = smem;             // [2][2][128][64]
  unsigned short* Bs = smem + 32768;
  int* rowIdxL = (int*)(smem + 65536);

  int tid = threadIdx.x, w = tid >> 6, lane = tid & 63;
  if (tid < 256) rowIdxL[tid] = idxp[row0 + tid];
  __syncthreads();

  int rbase = w * 8 + (lane >> 3);
  int colp  = 8 * ((lane & 7) ^ (lane >> 3));
  const unsigned short* gAp[2][2];
  const unsigned short* gBp[2][2];
#pragma unroll
  for (int hf = 0; hf < 2; ++hf)
#pragma unroll
    for (int L = 0; L < 2; ++L) {
      int r = hf * 128 + L * 64 + rbase;
      int arow = FIRST ? rowIdxL[r] : (row0 + r);
      gAp[hf][L] = A  + (size_t)arow * K + colp;
      gBp[hf][L] = Bt + (size_t)(col0 + r) * K + colp;
    }

  auto stage_half = [&](int n) {
    int T = n >> 2, j = n & 3;
    int half = j >> 1;
    bool isA = (j == 0) || (j == 3);
    unsigned short* base =
        (isA ? As : Bs) + (size_t)((T & 1) * 16384 + half * 8192 + w * 512);
    const unsigned short* s0 = (isA ? gAp[half][0] : gBp[half][0]) + T * 64;
    const unsigned short* s1 = (isA ? gAp[half][1] : gBp[half][1]) + T * 64;
    async16(s0, base);
    async16(s1, base + 4096);
  };

  f32x4 acc[4][4][2];
#pragma unroll
  for (int q = 0; q < 4; ++q)
#pragma unroll
    for (int mi = 0; mi < 4; ++mi)
#pragma unroll
      for (int ni = 0; ni < 2; ++ni) acc[q][mi][ni] = (f32x4){0.f, 0.f, 0.f, 0.f};

  int qr = (w >> 2) * 64, qc = (w & 3) * 32;
  int fr = lane & 15, khalf = lane >> 4;

#pragma unroll
  for (int n = 0; n < 6; ++n) stage_half(n);
  asm volatile("s_waitcnt vmcnt(4)" ::: "memory");
  __builtin_amdgcn_s_barrier();

  for (int t = 0; t < NKT; ++t) {
    int buf = t & 1;
#pragma unroll
    for (int q = 0; q < 4; ++q) {
      const int ah = q >> 1, bh = q & 1;
      unsigned short* Abase = As + (size_t)(buf * 16384 + ah * 8192);
      unsigned short* Bbase = Bs + (size_t)(buf * 16384 + bh * 8192);
      short8 af[4][2], bfr[2][2];
#pragma unroll
      for (int mi = 0; mi < 4; ++mi)
#pragma unroll
        for (int s = 0; s < 2; ++s) {
          int row = qr + mi * 16 + fr;
          af[mi][s] = *(const short8*)&Abase[row * 64 +
                        ((s * 32 + khalf * 8) ^ ((row & 7) << 3))];
        }
#pragma unroll
      for (int ni = 0; ni < 2; ++ni)
#pragma unroll
        for (int s = 0; s < 2; ++s) {
          int row = qc + ni * 16 + fr;
          bfr[ni][s] = *(const short8*)&Bbase[row * 64 +
                        ((s * 32 + khalf * 8) ^ ((row & 7) << 3))];
        }
      int n = t * 4 + q + 6;
      if (n < NH) stage_half(n);
      __builtin_amdgcn_s_barrier();
      asm volatile("s_waitcnt lgkmcnt(0)" ::: "memory");
      __builtin_amdgcn_sched_barrier(0);
      __builtin_amdgcn_s_setprio(1);
#pragma unroll
      for (int mi = 0; mi < 4; ++mi)
#pragma unroll
        for (int ni = 0; ni < 2; ++ni)
#pragma unroll
          for (int s = 0; s < 2; ++s)
            acc[q][mi][ni] = __builtin_amdgcn_mfma_f32_16x16x32_bf16(
                af[mi][s], bfr[ni][s], acc[q][mi][ni], 0, 0, 0);
      __builtin_amdgcn_s_setprio(0);
      __builtin_amdgcn_sched_barrier(0);
      if (q == 3 && t < NKT - 1) {
        if (t < NKT - 2) { asm volatile("s_waitcnt vmcnt(4)" ::: "memory"); }
        else             { asm volatile("s_waitcnt vmcnt(0)" ::: "memory"); }
        __builtin_amdgcn_sched_barrier(0);
      }
      __builtin_amdgcn_s_barrier();
    }
  }

  int cl = lane & 15, rq = lane >> 4;
#pragma unroll
  for (int q = 0; q < 4; ++q) {
    const int ah = q >> 1, bh = q & 1;
#pragma unroll
    for (int mi = 0; mi < 4; ++mi) {
#pragma unroll
      for (int ni = 0; ni < 2; ++ni) {
        int col = col0 + bh * 128 + qc + ni * 16 + cl;
        float bv = bias[col];
#pragma unroll
        for (int r2 = 0; r2 < 4; ++r2) {
          int rloc = ah * 128 + qr + mi * 16 + rq * 4 + r2;
          int grow = row0 + rloc;
          float val = acc[q][mi][ni][r2] + bv;
          if (FIRST) {
            val = val > 0.f ? val : 0.f;
            Hout[(size_t)grow * N + col] = f2bf(val);
          } else if (grow < cnt) {
            int tok = rowIdxL[rloc];
            Cout[(size_t)tok * DIM + col] = val;
          }
        }
      }
    }
  }
}

// ---------------------------------------------------------------------------
// GEMM2: 256x128 tile (8 col-tiles -> 512 blocks, ~256 active = full machine).
// A = h compact [256 rows, 2 halves], B = W2T [128 rows, 1 half]. 2 phases per
// K-tile (q=ah). Stream [A0,A1,B0]; stage-slot safety:
//   q0 stages A1(t+1),B0(t+1)  (old copies last read in PREVIOUS phase)
//   q1 stages A0(t+2)          (A0(t) last read in q0 of this tile)
//   boundary vmcnt(2) == exactly tile t+1's 3 half-tiles landed.
// Epilogue: scatter fp32 acc+b2 to out at idx[row].
// ---------------------------------------------------------------------------
template<int K>
__global__ __launch_bounds__(512, 1) void gemm8_n128_kernel(
    const unsigned short* __restrict__ A, const unsigned short* __restrict__ Bt,
    const float* __restrict__ bias, const int* __restrict__ idxp,
    const int* __restrict__ counter, float* __restrict__ Cout)
{
  constexpr int NT = DIM / 128;          // 8 column tiles
  constexpr int NKT = K / 64;

  int xcd = blockIdx.x & 7, lin = blockIdx.x >> 3;
  int rowb = (lin / NT) * 8 + xcd;
  int colb = lin % NT;

  int cnt = *counter;
  int row0 = rowb * 256;
  if (row0 >= cnt) return;
  int col0 = colb * 128;

  extern __shared__ unsigned short smem[];
  unsigned short* As = smem;             // [2][2][128][64]  64 KB
  unsigned short* Bs = smem + 32768;     // [2][128][64]     32 KB
  int* rowIdxL = (int*)(smem + 49152);   // 256 ints

  int tid = threadIdx.x, w = tid >> 6, lane = tid & 63;
  if (tid < 256) rowIdxL[tid] = idxp[row0 + tid];
  __syncthreads();

  int rbase = w * 8 + (lane >> 3);
  int colp  = 8 * ((lane & 7) ^ (lane >> 3));
  const unsigned short* gAp[2][2];       // [half][L]
  const unsigned short* gBp[2];          // [L]
#pragma unroll
  for (int hf = 0; hf < 2; ++hf)
#pragma unroll
    for (int L = 0; L < 2; ++L)
      gAp[hf][L] = A + (size_t)(row0 + hf * 128 + L * 64 + rbase) * K + colp;
#pragma unroll
  for (int L = 0; L < 2; ++L)
    gBp[L] = Bt + (size_t)(col0 + L * 64 + rbase) * K + colp;

  auto stageA = [&](int t, int hf) {
    unsigned short* base = As + (size_t)((t & 1) * 16384 + hf * 8192 + w * 512);
    async16(gAp[hf][0] + t * 64, base);
    async16(gAp[hf][1] + t * 64, base + 4096);
  };
  auto stageB = [&](int t) {
    unsigned short* base = Bs + (size_t)((t & 1) * 8192 + w * 512);
    async16(gBp[0] + t * 64, base);
    async16(gBp[1] + t * 64, base + 4096);
  };

  f32x4 acc[2][4][2];
#pragma unroll
  for (int q = 0; q < 2; ++q)
#pragma unroll
    for (int mi = 0; mi < 4; ++mi)
#pragma unroll
      for (int ni = 0; ni < 2; ++ni) acc[q][mi][ni] = (f32x4){0.f, 0.f, 0.f, 0.f};

  int qr = (w >> 2) * 64, qc = (w & 3) * 32;
  int fr = lane & 15, khalf = lane >> 4;

  // prologue: A0(0),A1(0),B0(0),A0(1) staged; first 3 landed (vmcnt(2))
  stageA(0, 0); stageA(0, 1); stageB(0); stageA(1, 0);
  asm volatile("s_waitcnt vmcnt(2)" ::: "memory");
  __builtin_amdgcn_s_barrier();

  for (int t = 0; t < NKT; ++t) {
    int buf = t & 1;
#pragma unroll
    for (int q = 0; q < 2; ++q) {
      unsigned short* Abase = As + (size_t)(buf * 16384 + q * 8192);
      unsigned short* Bbase = Bs + (size_t)(buf * 8192);
      short8 af[4][2], bfr[2][2];
#pragma unroll
      for (int mi = 0; mi < 4; ++mi)
#pragma unroll
        for (int s = 0; s < 2; ++s) {
          int row = qr + mi * 16 + fr;
          af[mi][s] = *(const short8*)&Abase[row * 64 +
                        ((s * 32 + khalf * 8) ^ ((row & 7) << 3))];
        }
#pragma unroll
      for (int ni = 0; ni < 2; ++ni)
#pragma unroll
        for (int s = 0; s < 2; ++s) {
          int row = qc + ni * 16 + fr;
          bfr[ni][s] = *(const short8*)&Bbase[row * 64 +
                        ((s * 32 + khalf * 8) ^ ((row & 7) << 3))];
        }
      if (q == 0) {
        if (t + 1 < NKT) { stageA(t + 1, 1); stageB(t + 1); }
      } else {
        if (t + 2 < NKT) { stageA(t + 2, 0); }
      }
      __builtin_amdgcn_s_barrier();
      asm volatile("s_waitcnt lgkmcnt(0)" ::: "memory");
      __builtin_amdgcn_sched_barrier(0);
      __builtin_amdgcn_s_setprio(1);
#pragma unroll
      for (int mi = 0; mi < 4; ++mi)
#pragma unroll
        for (int ni = 0; ni < 2; ++ni)
#pragma unroll
          for (int s = 0; s < 2; ++s)
            acc[q][mi][ni] = __builtin_amdgcn_mfma_f32_16x16x32_bf16(
                af[mi][s], bfr[ni][s], acc[q][mi][ni], 0, 0, 0);
      __builtin_amdgcn_s_setprio(0);
      __builtin_amdgcn_sched_barrier(0);
      if (q == 1 && t < NKT - 1) {
        if (t + 2 < NKT) { asm volatile("s_waitcnt vmcnt(2)" ::: "memory"); }
        else             { asm volatile("s_waitcnt vmcnt(0)" ::: "memory"); }
        __builtin_amdgcn_sched_barrier(0);
      }
      __builtin_amdgcn_s_barrier();
    }
  }

  // epilogue: C/D layout col = lane&15, row = (lane>>4)*4 + reg; scatter
  int cl = lane & 15, rq = lane >> 4;
#pragma unroll
  for (int q = 0; q < 2; ++q) {
#pragma unroll
    for (int mi = 0; mi < 4; ++mi) {
#pragma unroll
      for (int ni = 0; ni < 2; ++ni) {
        int col = col0 + qc + ni * 16 + cl;
        float bv = bias[col];
#pragma unroll
        for (int r2 = 0; r2 < 4; ++r2) {
          int rloc = q * 128 + qr + mi * 16 + rq * 4 + r2;
          int grow = row0 + rloc;
          if (grow < cnt) {
            int tok = rowIdxL[rloc];
            Cout[(size_t)tok * DIM + col] = acc[q][mi][ni][r2] + bv;
          }
        }
      }
    }
  }
}

// ---------------------------------------------------------------------------
extern "C" void kernel_launch(void* const* d_in, const int* in_sizes, int n_in,
                              void* d_out, int out_size, void* d_ws, size_t ws_size,
                              hipStream_t stream)
{
  const float* x  = (const float*)d_in[0];
  const float* Wr = (const float*)d_in[1];
  const float* br = (const float*)d_in[2];
  const float* W1 = (const float*)d_in[3];
  const float* b1 = (const float*)d_in[4];
  const float* W2 = (const float*)d_in[5];
  const float* b2 = (const float*)d_in[6];
  float* out = (float*)d_out;

  char* ws = (char*)d_ws;
  int* counter        = (int*)ws;                               // 4 B (zeroed)
  int* idx            = (int*)(ws + 256);                       // 64 KB (zeroed)
  unsigned short* xb  = (unsigned short*)(ws + (1ull  << 20));  // 32 MB bf16 x
  unsigned short* W1T = (unsigned short*)(ws + (34ull << 20));  // 8 MB  W1^T [4096][1024]
  unsigned short* W2T = (unsigned short*)(ws + (44ull << 20));  // 8 MB  W2^T [1024][4096]
  unsigned short* h   = (unsigned short*)(ws + (54ull << 20));  // 128 MB bf16 h

  constexpr int LDS_G1 = 132096;
  constexpr int LDS_G2 = 99328;
  hipFuncSetAttribute(reinterpret_cast<const void*>(&gemm8_kernel<HID, DIM, true>),
                      hipFuncAttributeMaxDynamicSharedMemorySize, LDS_G1);
  hipFuncSetAttribute(reinterpret_cast<const void*>(&gemm8_n128_kernel<HID>),
                      hipFuncAttributeMaxDynamicSharedMemorySize, LDS_G2);

  hipMemsetAsync(ws, 0, 256 + TOKENS * 4, stream);  // counter + idx

  router_kernel<<<TOKENS / 16, 256, 0, stream>>>(x, Wr, br, out, xb, idx, counter);
  transpose_cast_kernel<<<dim3(HID / 32, DIM / 32), 256, 0, stream>>>(W1, W1T, DIM, HID);
  transpose_cast_kernel<<<dim3(DIM / 32, HID / 32), 256, 0, stream>>>(W2, W2T, HID, DIM);
  frac_kernel<<<1, 1, 0, stream>>>(counter, out + (size_t)TOKENS * DIM);

  gemm8_kernel<HID, DIM, true><<<(HID / 256) * (TOKENS / 256), 512, LDS_G1, stream>>>(
      xb, W1T, b1, idx, counter, h, nullptr);
  gemm8_n128_kernel<HID><<<(DIM / 128) * (TOKENS / 256), 512, LDS_G2, stream>>>(
      h, W2T, b2, idx, counter, out);
}